// Round 2
// baseline (2187.250 us; speedup 1.0000x reference)
//
#include <hip/hip_runtime.h>
#include <hip/hip_bf16.h>

#define NUM_USERS 60000
#define NUM_ITEMS 40000
#define NUM_NODES 100000
#define EMB 64
#define HID 32
#define N_EDGES 1600000
#define BATCH 16384

// ---------------------------------------------------------------------------
// Layer-1 dense: H1[n][j] = gc1_b[j] + sum_k node_feat[n][k] * gc1_w[j][k]
// node_feat = concat(user_emb, item_emb). One thread per node.
// ---------------------------------------------------------------------------
__global__ __launch_bounds__(256) void k_linear1(
    const float* __restrict__ ue, const float* __restrict__ ie,
    const float* __restrict__ w, const float* __restrict__ b,
    float* __restrict__ out)
{
    __shared__ float ws[HID * EMB];
    __shared__ float bs[HID];
    for (int i = threadIdx.x; i < HID * EMB; i += 256) ws[i] = w[i];
    if (threadIdx.x < HID) bs[threadIdx.x] = b[threadIdx.x];
    __syncthreads();

    int n = blockIdx.x * 256 + threadIdx.x;
    if (n >= NUM_NODES) return;
    const float* row = (n < NUM_USERS) ? ue + (size_t)n * EMB
                                       : ie + (size_t)(n - NUM_USERS) * EMB;
    float x[EMB];
    #pragma unroll
    for (int k4 = 0; k4 < EMB / 4; k4++) {
        float4 v = reinterpret_cast<const float4*>(row)[k4];
        x[4*k4+0] = v.x; x[4*k4+1] = v.y; x[4*k4+2] = v.z; x[4*k4+3] = v.w;
    }
    const float4* ws4 = reinterpret_cast<const float4*>(ws);
    float acc[HID];
    #pragma unroll
    for (int j = 0; j < HID; j++) {
        float a = bs[j];
        #pragma unroll
        for (int k4 = 0; k4 < EMB / 4; k4++) {
            float4 wv = ws4[j * (EMB/4) + k4];   // lane-uniform -> LDS broadcast
            a = fmaf(wv.x, x[4*k4+0], a);
            a = fmaf(wv.y, x[4*k4+1], a);
            a = fmaf(wv.z, x[4*k4+2], a);
            a = fmaf(wv.w, x[4*k4+3], a);
        }
        acc[j] = a;
    }
    float4* o4 = reinterpret_cast<float4*>(out + (size_t)n * HID);
    #pragma unroll
    for (int j4 = 0; j4 < HID / 4; j4++)
        o4[j4] = make_float4(acc[4*j4], acc[4*j4+1], acc[4*j4+2], acc[4*j4+3]);
}

// ---------------------------------------------------------------------------
// Layer-2 dense: H2[n][j] = gc2_b[j] + sum_k relu(agg1[n][k]) * gc2_w[j][k]
// ---------------------------------------------------------------------------
__global__ __launch_bounds__(256) void k_linear2(
    const float* __restrict__ agg1,
    const float* __restrict__ w, const float* __restrict__ b,
    float* __restrict__ out)
{
    __shared__ float ws[EMB * HID];
    __shared__ float bs[EMB];
    for (int i = threadIdx.x; i < EMB * HID; i += 256) ws[i] = w[i];
    if (threadIdx.x < EMB) bs[threadIdx.x] = b[threadIdx.x];
    __syncthreads();

    int n = blockIdx.x * 256 + threadIdx.x;
    if (n >= NUM_NODES) return;
    const float* row = agg1 + (size_t)n * HID;
    float x[HID];
    #pragma unroll
    for (int k4 = 0; k4 < HID / 4; k4++) {
        float4 v = reinterpret_cast<const float4*>(row)[k4];
        x[4*k4+0] = fmaxf(v.x, 0.f); x[4*k4+1] = fmaxf(v.y, 0.f);
        x[4*k4+2] = fmaxf(v.z, 0.f); x[4*k4+3] = fmaxf(v.w, 0.f);
    }
    const float4* ws4 = reinterpret_cast<const float4*>(ws);
    float acc[EMB];
    #pragma unroll
    for (int j = 0; j < EMB; j++) {
        float a = bs[j];
        #pragma unroll
        for (int k4 = 0; k4 < HID / 4; k4++) {
            float4 wv = ws4[j * (HID/4) + k4];
            a = fmaf(wv.x, x[4*k4+0], a);
            a = fmaf(wv.y, x[4*k4+1], a);
            a = fmaf(wv.z, x[4*k4+2], a);
            a = fmaf(wv.w, x[4*k4+3], a);
        }
        acc[j] = a;
    }
    float4* o4 = reinterpret_cast<float4*>(out + (size_t)n * EMB);
    #pragma unroll
    for (int j4 = 0; j4 < EMB / 4; j4++)
        o4[j4] = make_float4(acc[4*j4], acc[4*j4+1], acc[4*j4+2], acc[4*j4+3]);
}

// ---------------------------------------------------------------------------
// Edge scatter: agg[rows[e]][:] += vals[e] * H[cols[e]][:]
// One thread per (edge, 4-feature-quad). SH = log2(F/4).
// ---------------------------------------------------------------------------
template<int F, int SH>
__global__ __launch_bounds__(256) void k_scatter(
    const int* __restrict__ rows, const int* __restrict__ cols,
    const float* __restrict__ vals,
    const float* __restrict__ H, float* __restrict__ agg)
{
    unsigned tid = blockIdx.x * 256u + threadIdx.x;
    unsigned e = tid >> SH;
    unsigned q = tid & ((1u << SH) - 1u);
    if (e >= N_EDGES) return;
    int r = rows[e];
    int c = cols[e];
    float v = vals[e];
    float4 h = reinterpret_cast<const float4*>(H + (size_t)c * F)[q];
    float* dst = agg + (size_t)r * F + 4u * q;
    atomicAdd(dst + 0, v * h.x);
    atomicAdd(dst + 1, v * h.y);
    atomicAdd(dst + 2, v * h.z);
    atomicAdd(dst + 3, v * h.w);
}

// ---------------------------------------------------------------------------
// relu copy: out[i] = max(in[i], 0)  (float4 granularity)
// ---------------------------------------------------------------------------
__global__ __launch_bounds__(256) void k_relu_copy(
    const float* __restrict__ in, float* __restrict__ out, int n4)
{
    int i = blockIdx.x * 256 + threadIdx.x;
    if (i >= n4) return;
    float4 v = reinterpret_cast<const float4*>(in)[i];
    v.x = fmaxf(v.x, 0.f); v.y = fmaxf(v.y, 0.f);
    v.z = fmaxf(v.z, 0.f); v.w = fmaxf(v.w, 0.f);
    reinterpret_cast<float4*>(out)[i] = v;
}

// ---------------------------------------------------------------------------
// MLP head: 32 threads per sample, 8 samples per block.
// z = [h2[u]; h2[NUM_USERS+i]] (128) ; z1 = relu(p1_w z + p1_b) (32)
// score = sigmoid(p2_w z1 + p2_b)
// p1_w repacked in LDS as [k4][j][4] so lane-indexed reads are contiguous b128.
// ---------------------------------------------------------------------------
__global__ __launch_bounds__(256) void k_mlp(
    const int* __restrict__ uids, const int* __restrict__ iids,
    const float* __restrict__ uemb, const float* __restrict__ iemb,
    const float* __restrict__ p1w, const float* __restrict__ p1b,
    const float* __restrict__ p2w, const float* __restrict__ p2b,
    float* __restrict__ scores)
{
    __shared__ float w1t[2 * EMB * HID];   // [k4][j][4] packing, 16 KB
    __shared__ float zt[8][2 * EMB];       // 4 KB
    __shared__ float b1s[HID];
    __shared__ float w2s[HID];

    for (int i = threadIdx.x; i < HID * 2 * EMB; i += 256) {
        int j = i >> 7;          // 0..31
        int k = i & 127;         // 0..127
        int k4 = k >> 2, c = k & 3;
        w1t[k4 * 128 + j * 4 + c] = p1w[i];
    }
    if (threadIdx.x < HID) {
        b1s[threadIdx.x] = p1b[threadIdx.x];
        w2s[threadIdx.x] = p2w[threadIdx.x];
    }
    __syncthreads();

    int lg = threadIdx.x >> 5;   // sample within block, 0..7
    int j  = threadIdx.x & 31;
    int s  = blockIdx.x * 8 + lg;   // BATCH%8==0, always valid

    {
        int u  = uids[s];
        int it = iids[s];
        const float* bu = uemb + (size_t)u * EMB;
        const float* bi = iemb + (size_t)it * EMB;
        float* zs = zt[lg];
        zs[j]      = bu[j];
        zs[32 + j] = bu[32 + j];
        zs[64 + j] = bi[j];
        zs[96 + j] = bi[32 + j];
    }
    __syncthreads();

    const float*  zs = zt[lg];
    const float4* w4 = reinterpret_cast<const float4*>(w1t);
    const float4* z4 = reinterpret_cast<const float4*>(zs);
    float a = b1s[j];
    #pragma unroll
    for (int k4 = 0; k4 < 32; k4++) {
        float4 wv = w4[k4 * 32 + j];   // contiguous 16B per lane -> no conflict
        float4 zv = z4[k4];            // lane-uniform -> broadcast
        a = fmaf(wv.x, zv.x, a);
        a = fmaf(wv.y, zv.y, a);
        a = fmaf(wv.z, zv.z, a);
        a = fmaf(wv.w, zv.w, a);
    }
    a = fmaxf(a, 0.f);
    float part = a * w2s[j];
    #pragma unroll
    for (int m = 16; m >= 1; m >>= 1) part += __shfl_xor(part, m);
    if (j == 0) scores[s] = 1.f / (1.f + expf(-(part + p2b[0])));
}

// ---------------------------------------------------------------------------
extern "C" void kernel_launch(void* const* d_in, const int* in_sizes, int n_in,
                              void* d_out, int out_size, void* d_ws, size_t ws_size,
                              hipStream_t stream)
{
    const int*   user_ids = (const int*)  d_in[0];
    const int*   item_ids = (const int*)  d_in[1];
    const int*   adj_rows = (const int*)  d_in[2];
    const int*   adj_cols = (const int*)  d_in[3];
    const float* adj_vals = (const float*)d_in[4];
    const float* user_emb = (const float*)d_in[5];
    const float* item_emb = (const float*)d_in[6];
    const float* gc1_w    = (const float*)d_in[7];
    const float* gc1_b    = (const float*)d_in[8];
    const float* gc2_w    = (const float*)d_in[9];
    const float* gc2_b    = (const float*)d_in[10];
    const float* p1_w     = (const float*)d_in[11];
    const float* p1_b     = (const float*)d_in[12];
    const float* p2_w     = (const float*)d_in[13];
    const float* p2_b     = (const float*)d_in[14];

    float* out     = (float*)d_out;
    float* scores  = out;
    float* emb_out = out + BATCH;                       // 100000*64 floats

    // workspace layout (floats):
    //   H1  @ 0         (100000*32 = 3.2M)
    //   A1  @ 3.2M      (3.2M)
    //   H2  @ 6.4M      (6.4M)
    //   A2  @ 0         (6.4M, aliases H1+A1 -- dead by then)
    // peak = 12.8M floats = 51.2 MB
    float* ws_f = (float*)d_ws;
    float* H1 = ws_f;
    float* A1 = ws_f + 3200000;
    float* H2 = ws_f + 6400000;
    float* A2 = ws_f;

    hipMemsetAsync(A1, 0, (size_t)NUM_NODES * HID * sizeof(float), stream);
    k_linear1<<<(NUM_NODES + 255) / 256, 256, 0, stream>>>(
        user_emb, item_emb, gc1_w, gc1_b, H1);
    k_scatter<HID, 3><<<(N_EDGES * 8) / 256, 256, 0, stream>>>(
        adj_rows, adj_cols, adj_vals, H1, A1);
    k_linear2<<<(NUM_NODES + 255) / 256, 256, 0, stream>>>(
        A1, gc2_w, gc2_b, H2);
    hipMemsetAsync(A2, 0, (size_t)NUM_NODES * EMB * sizeof(float), stream);
    k_scatter<EMB, 4><<<(N_EDGES * 16) / 256, 256, 0, stream>>>(
        adj_rows, adj_cols, adj_vals, H2, A2);
    k_relu_copy<<<(NUM_NODES * EMB / 4 + 255) / 256, 256, 0, stream>>>(
        A2, emb_out, NUM_NODES * EMB / 4);
    k_mlp<<<BATCH / 8, 256, 0, stream>>>(
        user_ids, item_ids, emb_out, emb_out + (size_t)NUM_USERS * EMB,
        p1_w, p1_b, p2_w, p2_b, scores);
}

// Round 3
// 474.892 us; speedup vs baseline: 4.6058x; 4.6058x over previous
//
#include <hip/hip_runtime.h>
#include <hip/hip_bf16.h>

#define NUM_USERS 60000
#define NUM_ITEMS 40000
#define NUM_NODES 100000
#define EMB 64
#define HID 32
#define N_EDGES 1600000
#define BATCH 16384

// scan geometry: 98 blocks x 1024 elems = 100352 >= NUM_NODES+1
#define SCAN_BLOCKS 98

// workspace layout (4-byte units):
//   OFF   @ 0        : 100352 u32  (counts -> exclusive offsets -> end-offsets)
//   AUX   @ 100352   : 128 u32     (scan block sums)
//   PAIRS @ 100480   : 3.2M u32    (1.6M x {col, val} in CSR order)
//   BIG   @ 3300480  : 6.4M f32    (H1 [100000x32] first, then H2 [100000x64])
// peak = 38.8 MB.  A1 (relu(agg1), 100000x32) lives in d_out's emb region,
// which is dead until k_agg<64> overwrites it with the final embeddings.
#define WS_OFF   0
#define WS_AUX   100352
#define WS_PAIRS 100480
#define WS_BIG   3300480

// ---------------------------------------------------------------------------
// CSR build step 1: histogram of rows
// ---------------------------------------------------------------------------
__global__ __launch_bounds__(256) void k_hist(
    const int* __restrict__ rows, unsigned* __restrict__ cnt)
{
    int e = blockIdx.x * 256 + threadIdx.x;
    if (e < N_EDGES) atomicAdd(&cnt[rows[e]], 1u);
}

// ---------------------------------------------------------------------------
// CSR build step 2: exclusive scan of 100001 counts (3-kernel hierarchical)
// ---------------------------------------------------------------------------
__global__ __launch_bounds__(256) void k_scan1(
    unsigned* __restrict__ arr, unsigned* __restrict__ aux)
{
    __shared__ unsigned s[256];
    int i0 = blockIdx.x * 1024 + threadIdx.x * 4;
    unsigned a0 = (i0 + 0 <= NUM_NODES) ? arr[i0 + 0] : 0u;
    unsigned a1 = (i0 + 1 <= NUM_NODES) ? arr[i0 + 1] : 0u;
    unsigned a2 = (i0 + 2 <= NUM_NODES) ? arr[i0 + 2] : 0u;
    unsigned a3 = (i0 + 3 <= NUM_NODES) ? arr[i0 + 3] : 0u;
    unsigned local = a0 + a1 + a2 + a3;
    s[threadIdx.x] = local;
    __syncthreads();
    #pragma unroll
    for (int ofs = 1; ofs < 256; ofs <<= 1) {
        unsigned t = (threadIdx.x >= ofs) ? s[threadIdx.x - ofs] : 0u;
        __syncthreads();
        s[threadIdx.x] += t;
        __syncthreads();
    }
    unsigned r = s[threadIdx.x] - local;   // exclusive prefix of this thread
    if (threadIdx.x == 255) aux[blockIdx.x] = s[255];
    arr[i0 + 0] = r; r += a0;
    arr[i0 + 1] = r; r += a1;
    arr[i0 + 2] = r; r += a2;
    arr[i0 + 3] = r;
}

__global__ __launch_bounds__(128) void k_scan2(unsigned* __restrict__ aux)
{
    __shared__ unsigned s[128];
    unsigned v = (threadIdx.x < SCAN_BLOCKS) ? aux[threadIdx.x] : 0u;
    s[threadIdx.x] = v;
    __syncthreads();
    #pragma unroll
    for (int ofs = 1; ofs < 128; ofs <<= 1) {
        unsigned t = (threadIdx.x >= ofs) ? s[threadIdx.x - ofs] : 0u;
        __syncthreads();
        s[threadIdx.x] += t;
        __syncthreads();
    }
    if (threadIdx.x < SCAN_BLOCKS) aux[threadIdx.x] = s[threadIdx.x] - v;
}

__global__ __launch_bounds__(256) void k_scan3(
    unsigned* __restrict__ arr, const unsigned* __restrict__ aux)
{
    unsigned add = aux[blockIdx.x];
    int base = blockIdx.x * 1024 + threadIdx.x;
    #pragma unroll
    for (int j = 0; j < 4; j++) arr[base + j * 256] += add;
}

// ---------------------------------------------------------------------------
// CSR build step 3: permute edges into row-sorted order.
// Uses off[] itself as the cursor: afterwards off[r] = row_end[r], so
// row r's slice is [ (r ? off[r-1] : 0), off[r] ).
// ---------------------------------------------------------------------------
__global__ __launch_bounds__(256) void k_permute(
    const int* __restrict__ rows, const int* __restrict__ cols,
    const float* __restrict__ vals,
    unsigned* __restrict__ off, uint2* __restrict__ pairs)
{
    int e = blockIdx.x * 256 + threadIdx.x;
    if (e >= N_EDGES) return;
    int r = rows[e];
    unsigned slot = atomicAdd(&off[r], 1u);
    pairs[slot] = make_uint2((unsigned)cols[e], __float_as_uint(vals[e]));
}

// ---------------------------------------------------------------------------
// Atomic-free aggregation: out[n][:] = relu( sum_{e in row n} val_e * H[col_e][:] )
// One wave per node. Lanes = QUADS feature-quads x GROUPS parallel edges.
// Gather of one H row = QUADS consecutive float4 lanes = fully coalesced.
// ---------------------------------------------------------------------------
template<int F>
__global__ __launch_bounds__(256) void k_agg(
    const unsigned* __restrict__ off, const uint2* __restrict__ pairs,
    const float* __restrict__ H, float* __restrict__ out)
{
    constexpr int QUADS  = F / 4;       // 16 (F=64) or 8 (F=32)
    constexpr int GROUPS = 64 / QUADS;  // 4 or 8
    int wave = threadIdx.x >> 6;
    int lane = threadIdx.x & 63;
    int n = blockIdx.x * 4 + wave;
    if (n >= NUM_NODES) return;
    int q = lane & (QUADS - 1);
    int g = lane / QUADS;
    unsigned begin = (n == 0) ? 0u : off[n - 1];
    unsigned end   = off[n];
    float4 acc = make_float4(0.f, 0.f, 0.f, 0.f);
    for (unsigned k = begin + g; k < end; k += GROUPS) {
        uint2 p = pairs[k];                       // broadcast within group
        float v = __uint_as_float(p.y);
        float4 h = reinterpret_cast<const float4*>(H + (size_t)p.x * F)[q];
        acc.x = fmaf(v, h.x, acc.x);
        acc.y = fmaf(v, h.y, acc.y);
        acc.z = fmaf(v, h.z, acc.z);
        acc.w = fmaf(v, h.w, acc.w);
    }
    #pragma unroll
    for (int m = QUADS; m < 64; m <<= 1) {
        acc.x += __shfl_xor(acc.x, m);
        acc.y += __shfl_xor(acc.y, m);
        acc.z += __shfl_xor(acc.z, m);
        acc.w += __shfl_xor(acc.w, m);
    }
    if (g == 0) {
        acc.x = fmaxf(acc.x, 0.f); acc.y = fmaxf(acc.y, 0.f);
        acc.z = fmaxf(acc.z, 0.f); acc.w = fmaxf(acc.w, 0.f);
        reinterpret_cast<float4*>(out + (size_t)n * F)[q] = acc;
    }
}

// ---------------------------------------------------------------------------
// Layer-1 dense: H1[n][j] = gc1_b[j] + sum_k node_feat[n][k] * gc1_w[j][k]
// ---------------------------------------------------------------------------
__global__ __launch_bounds__(256) void k_linear1(
    const float* __restrict__ ue, const float* __restrict__ ie,
    const float* __restrict__ w, const float* __restrict__ b,
    float* __restrict__ out)
{
    __shared__ float ws[HID * EMB];
    __shared__ float bs[HID];
    for (int i = threadIdx.x; i < HID * EMB; i += 256) ws[i] = w[i];
    if (threadIdx.x < HID) bs[threadIdx.x] = b[threadIdx.x];
    __syncthreads();

    int n = blockIdx.x * 256 + threadIdx.x;
    if (n >= NUM_NODES) return;
    const float* row = (n < NUM_USERS) ? ue + (size_t)n * EMB
                                       : ie + (size_t)(n - NUM_USERS) * EMB;
    float x[EMB];
    #pragma unroll
    for (int k4 = 0; k4 < EMB / 4; k4++) {
        float4 v = reinterpret_cast<const float4*>(row)[k4];
        x[4*k4+0] = v.x; x[4*k4+1] = v.y; x[4*k4+2] = v.z; x[4*k4+3] = v.w;
    }
    const float4* ws4 = reinterpret_cast<const float4*>(ws);
    float acc[HID];
    #pragma unroll
    for (int j = 0; j < HID; j++) {
        float a = bs[j];
        #pragma unroll
        for (int k4 = 0; k4 < EMB / 4; k4++) {
            float4 wv = ws4[j * (EMB/4) + k4];   // lane-uniform -> broadcast
            a = fmaf(wv.x, x[4*k4+0], a);
            a = fmaf(wv.y, x[4*k4+1], a);
            a = fmaf(wv.z, x[4*k4+2], a);
            a = fmaf(wv.w, x[4*k4+3], a);
        }
        acc[j] = a;
    }
    float4* o4 = reinterpret_cast<float4*>(out + (size_t)n * HID);
    #pragma unroll
    for (int j4 = 0; j4 < HID / 4; j4++)
        o4[j4] = make_float4(acc[4*j4], acc[4*j4+1], acc[4*j4+2], acc[4*j4+3]);
}

// ---------------------------------------------------------------------------
// Layer-2 dense: H2[n][j] = gc2_b[j] + sum_k A1[n][k] * gc2_w[j][k]
// (A1 already has relu applied by k_agg<32>.)
// ---------------------------------------------------------------------------
__global__ __launch_bounds__(256) void k_linear2(
    const float* __restrict__ a1,
    const float* __restrict__ w, const float* __restrict__ b,
    float* __restrict__ out)
{
    __shared__ float ws[EMB * HID];
    __shared__ float bs[EMB];
    for (int i = threadIdx.x; i < EMB * HID; i += 256) ws[i] = w[i];
    if (threadIdx.x < EMB) bs[threadIdx.x] = b[threadIdx.x];
    __syncthreads();

    int n = blockIdx.x * 256 + threadIdx.x;
    if (n >= NUM_NODES) return;
    const float* row = a1 + (size_t)n * HID;
    float x[HID];
    #pragma unroll
    for (int k4 = 0; k4 < HID / 4; k4++) {
        float4 v = reinterpret_cast<const float4*>(row)[k4];
        x[4*k4+0] = v.x; x[4*k4+1] = v.y; x[4*k4+2] = v.z; x[4*k4+3] = v.w;
    }
    const float4* ws4 = reinterpret_cast<const float4*>(ws);
    float acc[EMB];
    #pragma unroll
    for (int j = 0; j < EMB; j++) {
        float a = bs[j];
        #pragma unroll
        for (int k4 = 0; k4 < HID / 4; k4++) {
            float4 wv = ws4[j * (HID/4) + k4];
            a = fmaf(wv.x, x[4*k4+0], a);
            a = fmaf(wv.y, x[4*k4+1], a);
            a = fmaf(wv.z, x[4*k4+2], a);
            a = fmaf(wv.w, x[4*k4+3], a);
        }
        acc[j] = a;
    }
    float4* o4 = reinterpret_cast<float4*>(out + (size_t)n * EMB);
    #pragma unroll
    for (int j4 = 0; j4 < EMB / 4; j4++)
        o4[j4] = make_float4(acc[4*j4], acc[4*j4+1], acc[4*j4+2], acc[4*j4+3]);
}

// ---------------------------------------------------------------------------
// MLP head: 32 threads per sample, 8 samples per block.
// ---------------------------------------------------------------------------
__global__ __launch_bounds__(256) void k_mlp(
    const int* __restrict__ uids, const int* __restrict__ iids,
    const float* __restrict__ uemb, const float* __restrict__ iemb,
    const float* __restrict__ p1w, const float* __restrict__ p1b,
    const float* __restrict__ p2w, const float* __restrict__ p2b,
    float* __restrict__ scores)
{
    __shared__ float w1t[2 * EMB * HID];   // [k4][j][4] packing
    __shared__ float zt[8][2 * EMB];
    __shared__ float b1s[HID];
    __shared__ float w2s[HID];

    for (int i = threadIdx.x; i < HID * 2 * EMB; i += 256) {
        int j = i >> 7;
        int k = i & 127;
        int k4 = k >> 2, c = k & 3;
        w1t[k4 * 128 + j * 4 + c] = p1w[i];
    }
    if (threadIdx.x < HID) {
        b1s[threadIdx.x] = p1b[threadIdx.x];
        w2s[threadIdx.x] = p2w[threadIdx.x];
    }
    __syncthreads();

    int lg = threadIdx.x >> 5;
    int j  = threadIdx.x & 31;
    int s  = blockIdx.x * 8 + lg;

    {
        int u  = uids[s];
        int it = iids[s];
        const float* bu = uemb + (size_t)u * EMB;
        const float* bi = iemb + (size_t)it * EMB;
        float* zs = zt[lg];
        zs[j]      = bu[j];
        zs[32 + j] = bu[32 + j];
        zs[64 + j] = bi[j];
        zs[96 + j] = bi[32 + j];
    }
    __syncthreads();

    const float*  zs = zt[lg];
    const float4* w4 = reinterpret_cast<const float4*>(w1t);
    const float4* z4 = reinterpret_cast<const float4*>(zs);
    float a = b1s[j];
    #pragma unroll
    for (int k4 = 0; k4 < 32; k4++) {
        float4 wv = w4[k4 * 32 + j];
        float4 zv = z4[k4];
        a = fmaf(wv.x, zv.x, a);
        a = fmaf(wv.y, zv.y, a);
        a = fmaf(wv.z, zv.z, a);
        a = fmaf(wv.w, zv.w, a);
    }
    a = fmaxf(a, 0.f);
    float part = a * w2s[j];
    #pragma unroll
    for (int m = 16; m >= 1; m >>= 1) part += __shfl_xor(part, m);
    if (j == 0) scores[s] = 1.f / (1.f + expf(-(part + p2b[0])));
}

// ---------------------------------------------------------------------------
extern "C" void kernel_launch(void* const* d_in, const int* in_sizes, int n_in,
                              void* d_out, int out_size, void* d_ws, size_t ws_size,
                              hipStream_t stream)
{
    const int*   user_ids = (const int*)  d_in[0];
    const int*   item_ids = (const int*)  d_in[1];
    const int*   adj_rows = (const int*)  d_in[2];
    const int*   adj_cols = (const int*)  d_in[3];
    const float* adj_vals = (const float*)d_in[4];
    const float* user_emb = (const float*)d_in[5];
    const float* item_emb = (const float*)d_in[6];
    const float* gc1_w    = (const float*)d_in[7];
    const float* gc1_b    = (const float*)d_in[8];
    const float* gc2_w    = (const float*)d_in[9];
    const float* gc2_b    = (const float*)d_in[10];
    const float* p1_w     = (const float*)d_in[11];
    const float* p1_b     = (const float*)d_in[12];
    const float* p2_w     = (const float*)d_in[13];
    const float* p2_b     = (const float*)d_in[14];

    float* out     = (float*)d_out;
    float* scores  = out;
    float* emb_out = out + BATCH;                       // 100000*64 floats

    unsigned* ws_u = (unsigned*)d_ws;
    unsigned* off   = ws_u + WS_OFF;
    unsigned* aux   = ws_u + WS_AUX;
    uint2*    pairs = (uint2*)(ws_u + WS_PAIRS);
    float*    BIG   = (float*)(ws_u + WS_BIG);
    float*    H1    = BIG;            // 100000 x 32
    float*    H2    = BIG;            // 100000 x 64 (after H1 is dead)
    float*    A1    = emb_out;        // 100000 x 32, dead before agg2 overwrites

    const int EDGE_BLOCKS = (N_EDGES + 255) / 256;

    // ---- CSR build (shared by both layers) ----
    hipMemsetAsync(off, 0, (size_t)(NUM_NODES + 1) * sizeof(unsigned), stream);
    k_hist<<<EDGE_BLOCKS, 256, 0, stream>>>(adj_rows, off);
    k_scan1<<<SCAN_BLOCKS, 256, 0, stream>>>(off, aux);
    k_scan2<<<1, 128, 0, stream>>>(aux);
    k_scan3<<<SCAN_BLOCKS, 256, 0, stream>>>(off, aux);
    k_permute<<<EDGE_BLOCKS, 256, 0, stream>>>(adj_rows, adj_cols, adj_vals, off, pairs);

    // ---- layer 1 ----
    k_linear1<<<(NUM_NODES + 255) / 256, 256, 0, stream>>>(
        user_emb, item_emb, gc1_w, gc1_b, H1);
    k_agg<HID><<<(NUM_NODES + 3) / 4, 256, 0, stream>>>(off, pairs, H1, A1);

    // ---- layer 2 ----
    k_linear2<<<(NUM_NODES + 255) / 256, 256, 0, stream>>>(
        A1, gc2_w, gc2_b, H2);
    k_agg<EMB><<<(NUM_NODES + 3) / 4, 256, 0, stream>>>(off, pairs, H2, emb_out);

    // ---- MLP head ----
    k_mlp<<<BATCH / 8, 256, 0, stream>>>(
        user_ids, item_ids, emb_out, emb_out + (size_t)NUM_USERS * EMB,
        p1_w, p1_b, p2_w, p2_b, scores);
}